// Round 8
// baseline (305.549 us; speedup 1.0000x reference)
//
#include <hip/hip_runtime.h>

typedef __attribute__((ext_vector_type(8))) short short8;
typedef __attribute__((ext_vector_type(4))) float v4f;

__device__ __forceinline__ ushort f2bf(float x) {
    unsigned u = __float_as_uint(x);
    u = u + 0x7fffu + ((u >> 16) & 1u);     // round-to-nearest-even
    return (ushort)(u >> 16);
}
__device__ __forceinline__ float bflo(unsigned u) { return __uint_as_float(u << 16); }
__device__ __forceinline__ float bfhi(unsigned u) { return __uint_as_float(u & 0xffff0000u); }

// device-scope barrier among the first `nb` blocks (all co-resident: nb <= 128
// small blocks on 256 CUs; later blocks retire so stragglers always launch).
// Pattern (plain writes + threadfence + atomic flag + acquire spin) HW-validated
// in R7 across XCDs.
__device__ __forceinline__ void grid_barrier(int* flag, int nb, int tid) {
    __syncthreads();
    if (tid == 0) {
        __threadfence();                       // publish prior writes device-wide
        atomicAdd(flag, 1);
        while (__hip_atomic_load(flag, __ATOMIC_ACQUIRE,
                                 __HIP_MEMORY_SCOPE_AGENT) < nb)
            __builtin_amdgcn_s_sleep(1);
    }
    __syncthreads();
}

// K0: pure converts. blocks [0,nfb): feat fp32 -> bf16 feat16 (8 elems/thread);
// blocks [nfb, nfb+128): [W_src;W_skip] -> bf16 Wb[256][128].
__global__ __launch_bounds__(256) void k0_conv(
    const float* __restrict__ feat, const float* __restrict__ Wsrc,
    const float* __restrict__ Wskip, ushort* __restrict__ feat16,
    ushort* __restrict__ Wb, int nfb, int total_feat)
{
    int b = blockIdx.x;
    if (b < nfb) {
        int i = (b * 256 + threadIdx.x) * 8;
        if (i < total_feat) {
            const float4* p = (const float4*)(feat + i);
            float4 f0 = p[0], f1 = p[1];
            short8 v;
            v[0] = (short)f2bf(f0.x); v[1] = (short)f2bf(f0.y);
            v[2] = (short)f2bf(f0.z); v[3] = (short)f2bf(f0.w);
            v[4] = (short)f2bf(f1.x); v[5] = (short)f2bf(f1.y);
            v[6] = (short)f2bf(f1.z); v[7] = (short)f2bf(f1.w);
            *(short8*)(feat16 + i) = v;
        }
    } else {
        int i = (b - nfb) * 256 + threadIdx.x;    // 0..32767
        float v = (i < 16384) ? Wsrc[i] : Wskip[i - 16384];
        Wb[i] = f2bf(v);
    }
}

// MEGA: blocks [0,nbs): full CSR build (hist -> scan -> fill) with internal
// device barriers. Blocks [nbs, nbs+nbg): LDS-free bf16 MFMA projection GEMM
// (+ fused el/er). The two paths are independent and overlap.
__global__ __launch_bounds__(256) void k_mega(
    const ushort* __restrict__ feat16, const ushort* __restrict__ Wb,
    const float* __restrict__ bsrc, const float* __restrict__ bskip,
    const float* __restrict__ attn_l, const float* __restrict__ attn_r,
    ushort* __restrict__ feat_src, ushort* __restrict__ skip_bf,
    float* __restrict__ el, float* __restrict__ er, int n, int E_,
    const int* __restrict__ src, const int* __restrict__ dst,
    int* __restrict__ counts, int* __restrict__ row_start,
    int* __restrict__ cursor, int* __restrict__ blocksum,
    int* __restrict__ flags, int* __restrict__ csr_src, int nbs)
{
    __shared__ int sdata[256];
    const int tid = threadIdx.x;

    if (blockIdx.x < nbs) {
        // ================= CSR path =================
        const int sb = blockIdx.x;
        const int stride = nbs * 256;

        // Phase A: histogram (non-returning device atomics, fire-and-forget)
        for (int e = sb * 256 + tid; e < E_; e += stride)
            atomicAdd(&counts[dst[e]], 1);
        grid_barrier(&flags[0], nbs, tid);

        // Phase B: local exclusive scan of counts[sb*1024 .. +1024)
        int base = sb * 1024 + tid * 4;
        int v[4]; int s = 0;
        #pragma unroll
        for (int k = 0; k < 4; ++k) {
            int idx = base + k;
            v[k] = (idx < n) ? __hip_atomic_load(&counts[idx], __ATOMIC_RELAXED,
                                                 __HIP_MEMORY_SCOPE_AGENT) : 0;
            s += v[k];
        }
        sdata[tid] = s;
        __syncthreads();
        for (int off = 1; off < 256; off <<= 1) {
            int t = (tid >= off) ? sdata[tid - off] : 0;
            __syncthreads();
            sdata[tid] += t;
            __syncthreads();
        }
        if (tid == 255) blocksum[sb] = sdata[255];
        int run = (tid > 0) ? sdata[tid - 1] : 0;
        grid_barrier(&flags[1], nbs, tid);

        // global offsets: re-scan <=128 block sums in LDS
        if (tid < 128) {
            int bv = 0;
            if (tid < nbs)
                bv = __hip_atomic_load(&blocksum[tid], __ATOMIC_RELAXED,
                                       __HIP_MEMORY_SCOPE_AGENT);
            sdata[tid] = bv;
        }
        __syncthreads();
        for (int off = 1; off < 128; off <<= 1) {
            int t = 0;
            if (tid < 128 && tid >= off) t = sdata[tid - off];
            __syncthreads();
            if (tid < 128) sdata[tid] += t;
            __syncthreads();
        }
        int runout = run + ((sb > 0) ? sdata[sb - 1] : 0);
        #pragma unroll
        for (int k = 0; k < 4; ++k) {
            int idx = base + k;
            if (idx < n) { row_start[idx] = runout; cursor[idx] = runout; }
            if (idx == n) row_start[n] = E_;
            runout += v[k];
        }
        grid_barrier(&flags[2], nbs, tid);

        // Phase C: fill (2-wide unroll -> 2 returning atomics in flight)
        for (int e = sb * 256 + tid; e < E_; e += 2 * stride) {
            int e2 = e + stride;
            int d1 = dst[e], s1v = src[e];
            if (e2 < E_) {
                int d2 = dst[e2], s2v = src[e2];
                int p1 = atomicAdd(&cursor[d1], 1);
                int p2 = atomicAdd(&cursor[d2], 1);
                csr_src[p1] = s1v;
                csr_src[p2] = s2v;
            } else {
                int p1 = atomicAdd(&cursor[d1], 1);
                csr_src[p1] = s1v;
            }
        }
        return;
    }

    // ================= GEMM path (LDS-free) =================
    const int gb = blockIdx.x - nbs;
    const int wave = tid >> 6, lane = tid & 63;
    const int quad = lane >> 4, l16 = lane & 15;
    const int row0 = gb * 32;
    const int n0 = wave * 64;

    int r0i = row0 + l16, r1i = row0 + 16 + l16;
    int r0c = (r0i < n) ? r0i : n - 1;
    int r1c = (r1i < n) ? r1i : n - 1;
    const ushort* a0p = feat16 + (size_t)r0c * 128 + quad * 8;
    const ushort* a1p = feat16 + (size_t)r1c * 128 + quad * 8;

    // A fragments first (cold loads, get them in flight early)
    short8 a0[4], a1[4];
    #pragma unroll
    for (int k = 0; k < 4; ++k) {
        a0[k] = *(const short8*)(a0p + k * 32);
        a1[k] = *(const short8*)(a1p + k * 32);
    }

    const ushort* bp = Wb + (size_t)(n0 + l16) * 128 + quad * 8;
    v4f acc[2][4] = {};
    #pragma unroll
    for (int k = 0; k < 4; ++k) {
        short8 b[4];
        #pragma unroll
        for (int nt = 0; nt < 4; ++nt)
            b[nt] = *(const short8*)(bp + nt * 2048 + k * 32);
        #pragma unroll
        for (int nt = 0; nt < 4; ++nt) {
            acc[0][nt] = __builtin_amdgcn_mfma_f32_16x16x32_bf16(
                b[nt], a0[k], acc[0][nt], 0, 0, 0);   // swapped -> transposed tile
            acc[1][nt] = __builtin_amdgcn_mfma_f32_16x16x32_bf16(
                b[nt], a1[k], acc[1][nt], 0, 0, 0);
        }
    }

    // bias (cols cb..cb+3 contiguous per lane)
    #pragma unroll
    for (int nt = 0; nt < 4; ++nt) {
        int cb = n0 + nt * 16 + quad * 4;
        const float* bpb = (n0 < 128) ? (bsrc + cb) : (bskip + (cb - 128));
        float4 bias = *(const float4*)bpb;
        #pragma unroll
        for (int mt = 0; mt < 2; ++mt) {
            acc[mt][nt][0] += bias.x;
            acc[mt][nt][1] += bias.y;
            acc[mt][nt][2] += bias.z;
            acc[mt][nt][3] += bias.w;
        }
    }

    // store: pack 4 consecutive cols -> one 8B store per (mt,nt)
    #pragma unroll
    for (int mt = 0; mt < 2; ++mt) {
        int row = row0 + mt * 16 + l16;
        if (row < n) {
            #pragma unroll
            for (int nt = 0; nt < 4; ++nt) {
                int cb = n0 + nt * 16 + quad * 4;
                unsigned lo = (unsigned)f2bf(acc[mt][nt][0]) |
                              ((unsigned)f2bf(acc[mt][nt][1]) << 16);
                unsigned hi = (unsigned)f2bf(acc[mt][nt][2]) |
                              ((unsigned)f2bf(acc[mt][nt][3]) << 16);
                uint2 pv = make_uint2(lo, hi);
                if (n0 < 128) *(uint2*)(feat_src + (size_t)row * 128 + cb) = pv;
                else          *(uint2*)(skip_bf  + (size_t)row * 128 + (cb - 128)) = pv;
            }
        }
    }

    // el/er: waves 0,1 (cols < 128); in-register partial dots + shfl_xor(16,32)
    if (wave < 2) {
        const int hb = n0 >> 5;
        float4 al[4], ar[4];
        #pragma unroll
        for (int nt = 0; nt < 4; ++nt) {
            int cb = n0 + nt * 16 + quad * 4;
            al[nt] = *(const float4*)(attn_l + cb);
            ar[nt] = *(const float4*)(attn_r + cb);
        }
        #pragma unroll
        for (int mt = 0; mt < 2; ++mt) {
            float pl0 = 0.f, pl1 = 0.f, pr0 = 0.f, pr1 = 0.f;
            #pragma unroll
            for (int i = 0; i < 4; ++i) {
                float a0v = acc[mt][0][i], a1v = acc[mt][1][i];
                float a2v = acc[mt][2][i], a3v = acc[mt][3][i];
                const float* pal0 = (const float*)&al[0]; const float* pal1 = (const float*)&al[1];
                const float* pal2 = (const float*)&al[2]; const float* pal3 = (const float*)&al[3];
                const float* par0 = (const float*)&ar[0]; const float* par1 = (const float*)&ar[1];
                const float* par2 = (const float*)&ar[2]; const float* par3 = (const float*)&ar[3];
                pl0 = fmaf(a0v, pal0[i], fmaf(a1v, pal1[i], pl0));
                pl1 = fmaf(a2v, pal2[i], fmaf(a3v, pal3[i], pl1));
                pr0 = fmaf(a0v, par0[i], fmaf(a1v, par1[i], pr0));
                pr1 = fmaf(a2v, par2[i], fmaf(a3v, par3[i], pr1));
            }
            pl0 += __shfl_xor(pl0, 16); pl0 += __shfl_xor(pl0, 32);
            pl1 += __shfl_xor(pl1, 16); pl1 += __shfl_xor(pl1, 32);
            pr0 += __shfl_xor(pr0, 16); pr0 += __shfl_xor(pr0, 32);
            pr1 += __shfl_xor(pr1, 16); pr1 += __shfl_xor(pr1, 32);
            int row = row0 + mt * 16 + l16;
            if (lane < 16 && row < n) {
                *(float2*)(el + (size_t)row * 4 + hb) = make_float2(pl0, pl1);
                *(float2*)(er + (size_t)row * 4 + hb) = make_float2(pr0, pr1);
            }
        }
    }
}

// K3: fused softmax-aggregate + gate + LayerNorm + PReLU. 32 lanes per node
// (2 nodes/wave), proven 54 us @ 24 VGPR / 67% occ — unchanged from R7.
__global__ __launch_bounds__(256) void k3_fused(
    const int* __restrict__ row_start, const int* __restrict__ csr_src,
    const float* __restrict__ el, const float* __restrict__ er,
    const ushort* __restrict__ feat_src, const ushort* __restrict__ skip_bf,
    const float* __restrict__ Wg, const float* __restrict__ bg,
    const float* __restrict__ lng, const float* __restrict__ lnb,
    const float* __restrict__ pa, float* __restrict__ out, int n)
{
    int node = blockIdx.x * 8 + (threadIdx.x >> 5);
    if (node >= n) return;
    int l32 = threadIdx.x & 31;
    int j = l32 * 4;                       // cols j..j+3
    int h = l32 >> 3;                      // head

    int beg = row_start[node], end = row_start[node + 1];
    float er_h = er[(size_t)node * 4 + h];
    const ushort* fbase = feat_src + j;

    float ac0 = 0.f, ac1 = 0.f, ac2 = 0.f, ac3 = 0.f;
    float bc0 = 0.f, bc1 = 0.f, bc2 = 0.f, bc3 = 0.f;
    float wsA = 0.f, wsB = 0.f;

    for (int p0 = beg; p0 < end; p0 += 32) {
        int pv = p0 + l32;
        int sv = csr_src[pv < end ? pv : end - 1];   // coalesced, 32 edges/batch
        int cnt = end - p0; if (cnt > 32) cnt = 32;
        int i = 0;
        for (; i + 1 < cnt; i += 2) {
            int s0 = __shfl(sv, i, 32), s1 = __shfl(sv, i + 1, 32);
            float e0 = el[(size_t)s0 * 4 + h];
            float e1 = el[(size_t)s1 * 4 + h];
            uint2 u0 = *(const uint2*)(fbase + (size_t)s0 * 128);
            uint2 u1 = *(const uint2*)(fbase + (size_t)s1 * 128);
            float t0 = e0 + er_h, t1 = e1 + er_h;
            float w0 = __expf(t0 >= 0.f ? t0 : 0.2f * t0);
            float w1 = __expf(t1 >= 0.f ? t1 : 0.2f * t1);
            wsA += w0; wsB += w1;
            ac0 = fmaf(w0, bflo(u0.x), ac0); ac1 = fmaf(w0, bfhi(u0.x), ac1);
            ac2 = fmaf(w0, bflo(u0.y), ac2); ac3 = fmaf(w0, bfhi(u0.y), ac3);
            bc0 = fmaf(w1, bflo(u1.x), bc0); bc1 = fmaf(w1, bfhi(u1.x), bc1);
            bc2 = fmaf(w1, bflo(u1.y), bc2); bc3 = fmaf(w1, bfhi(u1.y), bc3);
        }
        if (i < cnt) {
            int s = __shfl(sv, i, 32);
            float t = el[(size_t)s * 4 + h] + er_h;
            float w = __expf(t >= 0.f ? t : 0.2f * t);
            uint2 u = *(const uint2*)(fbase + (size_t)s * 128);
            wsA += w;
            ac0 = fmaf(w, bflo(u.x), ac0); ac1 = fmaf(w, bfhi(u.x), ac1);
            ac2 = fmaf(w, bflo(u.y), ac2); ac3 = fmaf(w, bfhi(u.y), ac3);
        }
    }
    float wsum = wsA + wsB;
    float inv = (wsum > 0.f) ? 1.f / wsum : 0.f;   // deg-0 node -> rst = 0
    float r0 = (ac0 + bc0) * inv, r1 = (ac1 + bc1) * inv;
    float r2 = (ac2 + bc2) * inv, r3 = (ac3 + bc3) * inv;

    uint2 su = *(const uint2*)(skip_bf + (size_t)node * 128 + j);
    float s0 = bflo(su.x), s1 = bfhi(su.x), s2 = bflo(su.y), s3 = bfhi(su.y);

    float4 wg0 = *(const float4*)(Wg + j);
    float4 wg1 = *(const float4*)(Wg + 128 + j);
    float4 wg2 = *(const float4*)(Wg + 256 + j);
    float g = r0 * wg0.x + s0 * wg1.x + (r0 - s0) * wg2.x
            + r1 * wg0.y + s1 * wg1.y + (r1 - s1) * wg2.y
            + r2 * wg0.z + s2 * wg1.z + (r2 - s2) * wg2.z
            + r3 * wg0.w + s3 * wg1.w + (r3 - s3) * wg2.w;
    #pragma unroll
    for (int m = 1; m < 32; m <<= 1) g += __shfl_xor(g, m, 32);
    float gate = 1.f / (1.f + __expf(-(g + bg[0])));

    float x0 = gate * r0 + (1.f - gate) * s0;
    float x1 = gate * r1 + (1.f - gate) * s1;
    float x2 = gate * r2 + (1.f - gate) * s2;
    float x3 = gate * r3 + (1.f - gate) * s3;

    float sm = (x0 + x1) + (x2 + x3);
    float sq = (x0 * x0 + x1 * x1) + (x2 * x2 + x3 * x3);
    #pragma unroll
    for (int m = 1; m < 32; m <<= 1) {
        sm += __shfl_xor(sm, m, 32);
        sq += __shfl_xor(sq, m, 32);
    }
    float mu = sm * (1.f / 128.f);
    float var = sq * (1.f / 128.f) - mu * mu;
    float rs = rsqrtf(var + 1e-5f);
    float alpha = pa[0];
    float4 lg = *(const float4*)(lng + j);
    float4 lb = *(const float4*)(lnb + j);
    float y0 = (x0 - mu) * rs * lg.x + lb.x;
    float y1 = (x1 - mu) * rs * lg.y + lb.y;
    float y2 = (x2 - mu) * rs * lg.z + lb.z;
    float y3 = (x3 - mu) * rs * lg.w + lb.w;
    y0 = y0 >= 0.f ? y0 : alpha * y0;
    y1 = y1 >= 0.f ? y1 : alpha * y1;
    y2 = y2 >= 0.f ? y2 : alpha * y2;
    y3 = y3 >= 0.f ? y3 : alpha * y3;
    *(float4*)(out + (size_t)node * 128 + j) = make_float4(y0, y1, y2, y3);
}

extern "C" void kernel_launch(void* const* d_in, const int* in_sizes, int n_in,
                              void* d_out, int out_size, void* d_ws, size_t ws_size,
                              hipStream_t stream)
{
    const float* feat   = (const float*)d_in[0];
    const int*   src    = (const int*)d_in[1];
    const int*   dst    = (const int*)d_in[2];
    const float* Wsrc   = (const float*)d_in[3];
    const float* bsrc   = (const float*)d_in[4];
    const float* attn_l = (const float*)d_in[5];
    const float* attn_r = (const float*)d_in[6];
    const float* Wskip  = (const float*)d_in[7];
    const float* bskip  = (const float*)d_in[8];
    const float* Wg     = (const float*)d_in[9];
    const float* bg     = (const float*)d_in[10];
    const float* lng    = (const float*)d_in[11];
    const float* lnb    = (const float*)d_in[12];
    const float* pa     = (const float*)d_in[13];

    const int n = in_sizes[0] / 128;
    const int E = in_sizes[1];
    float* out = (float*)d_out;

    // workspace: el f32[4n] | er f32[4n] | feat_src bf16[128n] | skip bf16[128n]
    //  | Wb bf16[32768] | feat16 bf16[128n] | counts[n] | blocksum[128]
    //  | flags[4] | row_start[n+1] | cursor[n] | csr_src[E]
    float*  el       = (float*)d_ws;
    float*  er       = el + (size_t)n * 4;
    ushort* feat_src = (ushort*)(er + (size_t)n * 4);
    ushort* skip_bf  = feat_src + (size_t)n * 128;
    ushort* Wb       = skip_bf + (size_t)n * 128;
    ushort* feat16   = Wb + 32768;
    int*    counts    = (int*)(feat16 + (size_t)n * 128);
    int*    blocksum  = counts + n;
    int*    flags     = blocksum + 128;
    int*    row_start = flags + 4;
    int*    cursor    = row_start + (n + 1);
    int*    csr_src   = cursor + n;

    // zero counts + blocksum + flags in one memset
    hipMemsetAsync(counts, 0, (size_t)(n + 132) * sizeof(int), stream);

    int total_feat = n * 128;
    int nfb = (total_feat + 2047) / 2048;
    k0_conv<<<nfb + 128, 256, 0, stream>>>(feat, Wsrc, Wskip, feat16, Wb,
                                           nfb, total_feat);

    int nbs = (n + 1023) / 1024;          // CSR blocks (first, co-resident)
    int nbg = (n + 31) / 32;              // GEMM blocks
    k_mega<<<nbs + nbg, 256, 0, stream>>>(
        feat16, Wb, bsrc, bskip, attn_l, attn_r, feat_src, skip_bf, el, er,
        n, E, src, dst, counts, row_start, cursor, blocksum, flags, csr_src, nbs);

    k3_fused<<<(n + 7) / 8, 256, 0, stream>>>(
        row_start, csr_src, el, er, feat_src, skip_bf, Wg, bg, lng, lnb, pa, out, n);
}

// Round 9
// 276.738 us; speedup vs baseline: 1.1041x; 1.1041x over previous
//
#include <hip/hip_runtime.h>

typedef __attribute__((ext_vector_type(8))) short short8;
typedef __attribute__((ext_vector_type(4))) float v4f;

__device__ __forceinline__ ushort f2bf(float x) {
    unsigned u = __float_as_uint(x);
    u = u + 0x7fffu + ((u >> 16) & 1u);     // round-to-nearest-even
    return (ushort)(u >> 16);
}
__device__ __forceinline__ float bflo(unsigned u) { return __uint_as_float(u << 16); }
__device__ __forceinline__ float bfhi(unsigned u) { return __uint_as_float(u & 0xffff0000u); }

#define CPAD 16   // counter padding: one counter per 64B line (cuts line contention 16x)

// K0: rank pass + converts, one dispatch, independent block ranges.
// blocks [0, nrb): per-edge rank r = atomicAdd(count[dst]), rank[e] = r  (the ONLY atomic pass)
// blocks [nrb, nrb+nfb): feat fp32 -> bf16
// blocks [nrb+nfb, +128): [W_src;W_skip] -> bf16 Wb
__global__ __launch_bounds__(256) void k0_conv(
    const float* __restrict__ feat, const float* __restrict__ Wsrc,
    const float* __restrict__ Wskip, const int* __restrict__ dst,
    ushort* __restrict__ feat16, ushort* __restrict__ Wb,
    int* __restrict__ counts_p, int* __restrict__ rank,
    int nrb, int nfb, int total_feat, int E_)
{
    int b = blockIdx.x;
    if (b < nrb) {
        int e = b * 256 + threadIdx.x;
        if (e < E_) {
            int d = dst[e];
            int r = atomicAdd(&counts_p[(size_t)d * CPAD], 1);
            rank[e] = r;
        }
    } else if (b < nrb + nfb) {
        int i = ((b - nrb) * 256 + threadIdx.x) * 8;
        if (i < total_feat) {
            const float4* p = (const float4*)(feat + i);
            float4 f0 = p[0], f1 = p[1];
            short8 v;
            v[0] = (short)f2bf(f0.x); v[1] = (short)f2bf(f0.y);
            v[2] = (short)f2bf(f0.z); v[3] = (short)f2bf(f0.w);
            v[4] = (short)f2bf(f1.x); v[5] = (short)f2bf(f1.y);
            v[6] = (short)f2bf(f1.z); v[7] = (short)f2bf(f1.w);
            *(short8*)(feat16 + i) = v;
        }
    } else {
        int i = (b - nrb - nfb) * 256 + threadIdx.x;   // 0..32767
        float v = (i < 16384) ? Wsrc[i] : Wskip[i - 16384];
        Wb[i] = f2bf(v);
    }
}

// MEGA: blocks [0, nbs): scan of padded counts -> row_start (single spin-barrier,
// R7-proven pattern; nbs <= 128 co-resident blocks). Blocks [nbs, nbs+nbg):
// LDS-free bf16 MFMA projection GEMM + fused el/er. Independent, overlap.
__global__ __launch_bounds__(256) void k_mega(
    const ushort* __restrict__ feat16, const ushort* __restrict__ Wb,
    const float* __restrict__ bsrc, const float* __restrict__ bskip,
    const float* __restrict__ attn_l, const float* __restrict__ attn_r,
    ushort* __restrict__ feat_src, ushort* __restrict__ skip_bf,
    float* __restrict__ el, float* __restrict__ er, int n, int E_,
    const int* __restrict__ counts_p, int* __restrict__ row_start,
    int* __restrict__ blocksum, int* __restrict__ ready, int nbs)
{
    __shared__ int sdata[256];
    const int tid = threadIdx.x;

    if (blockIdx.x < nbs) {
        // ---- scan path ----
        int sb = blockIdx.x;
        int base = sb * 1024 + tid * 4;
        int v[4]; int s = 0;
        #pragma unroll
        for (int k = 0; k < 4; ++k) {
            int idx = base + k;
            v[k] = (idx < n) ? counts_p[(size_t)idx * CPAD] : 0;
            s += v[k];
        }
        sdata[tid] = s;
        __syncthreads();
        for (int off = 1; off < 256; off <<= 1) {
            int t = (tid >= off) ? sdata[tid - off] : 0;
            __syncthreads();
            sdata[tid] += t;
            __syncthreads();
        }
        if (tid == 255) {
            blocksum[sb] = sdata[255];
            __threadfence();
            atomicAdd(ready, 1);
        }
        int run = (tid > 0) ? sdata[tid - 1] : 0;
        if (tid == 0) {
            while (__hip_atomic_load(ready, __ATOMIC_ACQUIRE,
                                     __HIP_MEMORY_SCOPE_AGENT) < nbs)
                __builtin_amdgcn_s_sleep(2);
        }
        __syncthreads();
        if (tid < 128) {
            int bv = 0;
            if (tid < nbs)
                bv = __hip_atomic_load(&blocksum[tid], __ATOMIC_RELAXED,
                                       __HIP_MEMORY_SCOPE_AGENT);
            sdata[tid] = bv;
        }
        __syncthreads();
        for (int off = 1; off < 128; off <<= 1) {
            int t = 0;
            if (tid < 128 && tid >= off) t = sdata[tid - off];
            __syncthreads();
            if (tid < 128) sdata[tid] += t;
            __syncthreads();
        }
        int runout = run + ((sb > 0) ? sdata[sb - 1] : 0);
        #pragma unroll
        for (int k = 0; k < 4; ++k) {
            int idx = base + k;
            if (idx < n) row_start[idx] = runout;
            if (idx == n) row_start[n] = E_;
            runout += v[k];
        }
        return;
    }

    // ---- GEMM path (LDS-free; feat16/Wb are L1/L2-hot) ----
    const int gb = blockIdx.x - nbs;
    const int wave = tid >> 6, lane = tid & 63;
    const int quad = lane >> 4, l16 = lane & 15;
    const int row0 = gb * 32;
    const int n0 = wave * 64;

    int r0i = row0 + l16, r1i = row0 + 16 + l16;
    int r0c = (r0i < n) ? r0i : n - 1;
    int r1c = (r1i < n) ? r1i : n - 1;
    const ushort* a0p = feat16 + (size_t)r0c * 128 + quad * 8;
    const ushort* a1p = feat16 + (size_t)r1c * 128 + quad * 8;

    short8 a0[4], a1[4];
    #pragma unroll
    for (int k = 0; k < 4; ++k) {
        a0[k] = *(const short8*)(a0p + k * 32);
        a1[k] = *(const short8*)(a1p + k * 32);
    }

    const ushort* bp = Wb + (size_t)(n0 + l16) * 128 + quad * 8;
    v4f acc[2][4] = {};
    #pragma unroll
    for (int k = 0; k < 4; ++k) {
        short8 b[4];
        #pragma unroll
        for (int nt = 0; nt < 4; ++nt)
            b[nt] = *(const short8*)(bp + nt * 2048 + k * 32);
        #pragma unroll
        for (int nt = 0; nt < 4; ++nt) {
            acc[0][nt] = __builtin_amdgcn_mfma_f32_16x16x32_bf16(
                b[nt], a0[k], acc[0][nt], 0, 0, 0);   // swapped -> transposed tile
            acc[1][nt] = __builtin_amdgcn_mfma_f32_16x16x32_bf16(
                b[nt], a1[k], acc[1][nt], 0, 0, 0);
        }
    }

    #pragma unroll
    for (int nt = 0; nt < 4; ++nt) {
        int cb = n0 + nt * 16 + quad * 4;
        const float* bpb = (n0 < 128) ? (bsrc + cb) : (bskip + (cb - 128));
        float4 bias = *(const float4*)bpb;
        #pragma unroll
        for (int mt = 0; mt < 2; ++mt) {
            acc[mt][nt][0] += bias.x;
            acc[mt][nt][1] += bias.y;
            acc[mt][nt][2] += bias.z;
            acc[mt][nt][3] += bias.w;
        }
    }

    #pragma unroll
    for (int mt = 0; mt < 2; ++mt) {
        int row = row0 + mt * 16 + l16;
        if (row < n) {
            #pragma unroll
            for (int nt = 0; nt < 4; ++nt) {
                int cb = n0 + nt * 16 + quad * 4;
                unsigned lo = (unsigned)f2bf(acc[mt][nt][0]) |
                              ((unsigned)f2bf(acc[mt][nt][1]) << 16);
                unsigned hi = (unsigned)f2bf(acc[mt][nt][2]) |
                              ((unsigned)f2bf(acc[mt][nt][3]) << 16);
                uint2 pv = make_uint2(lo, hi);
                if (n0 < 128) *(uint2*)(feat_src + (size_t)row * 128 + cb) = pv;
                else          *(uint2*)(skip_bf  + (size_t)row * 128 + (cb - 128)) = pv;
            }
        }
    }

    if (wave < 2) {
        const int hb = n0 >> 5;
        float4 al[4], ar[4];
        #pragma unroll
        for (int nt = 0; nt < 4; ++nt) {
            int cb = n0 + nt * 16 + quad * 4;
            al[nt] = *(const float4*)(attn_l + cb);
            ar[nt] = *(const float4*)(attn_r + cb);
        }
        #pragma unroll
        for (int mt = 0; mt < 2; ++mt) {
            float pl0 = 0.f, pl1 = 0.f, pr0 = 0.f, pr1 = 0.f;
            #pragma unroll
            for (int i = 0; i < 4; ++i) {
                float a0v = acc[mt][0][i], a1v = acc[mt][1][i];
                float a2v = acc[mt][2][i], a3v = acc[mt][3][i];
                const float* pal0 = (const float*)&al[0]; const float* pal1 = (const float*)&al[1];
                const float* pal2 = (const float*)&al[2]; const float* pal3 = (const float*)&al[3];
                const float* par0 = (const float*)&ar[0]; const float* par1 = (const float*)&ar[1];
                const float* par2 = (const float*)&ar[2]; const float* par3 = (const float*)&ar[3];
                pl0 = fmaf(a0v, pal0[i], fmaf(a1v, pal1[i], pl0));
                pl1 = fmaf(a2v, pal2[i], fmaf(a3v, pal3[i], pl1));
                pr0 = fmaf(a0v, par0[i], fmaf(a1v, par1[i], pr0));
                pr1 = fmaf(a2v, par2[i], fmaf(a3v, par3[i], pr1));
            }
            pl0 += __shfl_xor(pl0, 16); pl0 += __shfl_xor(pl0, 32);
            pl1 += __shfl_xor(pl1, 16); pl1 += __shfl_xor(pl1, 32);
            pr0 += __shfl_xor(pr0, 16); pr0 += __shfl_xor(pr0, 32);
            pr1 += __shfl_xor(pr1, 16); pr1 += __shfl_xor(pr1, 32);
            int row = row0 + mt * 16 + l16;
            if (lane < 16 && row < n) {
                *(float2*)(el + (size_t)row * 4 + hb) = make_float2(pl0, pl1);
                *(float2*)(er + (size_t)row * 4 + hb) = make_float2(pr0, pr1);
            }
        }
    }
}

// fill2: atomic-free CSR fill. csr_src[row_start[dst[e]] + rank[e]] = src[e].
__global__ __launch_bounds__(256) void k_fill2(
    const int* __restrict__ src, const int* __restrict__ dst,
    const int* __restrict__ rank, const int* __restrict__ row_start,
    int* __restrict__ csr_src, int E_)
{
    int e = blockIdx.x * 256 + threadIdx.x;
    if (e >= E_) return;
    int d = dst[e];
    int r = rank[e];
    int s = src[e];
    csr_src[row_start[d] + r] = s;
}

// K3: fused softmax-aggregate + gate + LayerNorm + PReLU. 32 lanes per node
// (2 nodes/wave), proven 54 us @ 24 VGPR / 67% occ — unchanged from R7.
__global__ __launch_bounds__(256) void k3_fused(
    const int* __restrict__ row_start, const int* __restrict__ csr_src,
    const float* __restrict__ el, const float* __restrict__ er,
    const ushort* __restrict__ feat_src, const ushort* __restrict__ skip_bf,
    const float* __restrict__ Wg, const float* __restrict__ bg,
    const float* __restrict__ lng, const float* __restrict__ lnb,
    const float* __restrict__ pa, float* __restrict__ out, int n)
{
    int node = blockIdx.x * 8 + (threadIdx.x >> 5);
    if (node >= n) return;
    int l32 = threadIdx.x & 31;
    int j = l32 * 4;                       // cols j..j+3
    int h = l32 >> 3;                      // head

    int beg = row_start[node], end = row_start[node + 1];
    float er_h = er[(size_t)node * 4 + h];
    const ushort* fbase = feat_src + j;

    float ac0 = 0.f, ac1 = 0.f, ac2 = 0.f, ac3 = 0.f;
    float bc0 = 0.f, bc1 = 0.f, bc2 = 0.f, bc3 = 0.f;
    float wsA = 0.f, wsB = 0.f;

    for (int p0 = beg; p0 < end; p0 += 32) {
        int pv = p0 + l32;
        int sv = csr_src[pv < end ? pv : end - 1];   // coalesced, 32 edges/batch
        int cnt = end - p0; if (cnt > 32) cnt = 32;
        int i = 0;
        for (; i + 1 < cnt; i += 2) {
            int s0 = __shfl(sv, i, 32), s1 = __shfl(sv, i + 1, 32);
            float e0 = el[(size_t)s0 * 4 + h];
            float e1 = el[(size_t)s1 * 4 + h];
            uint2 u0 = *(const uint2*)(fbase + (size_t)s0 * 128);
            uint2 u1 = *(const uint2*)(fbase + (size_t)s1 * 128);
            float t0 = e0 + er_h, t1 = e1 + er_h;
            float w0 = __expf(t0 >= 0.f ? t0 : 0.2f * t0);
            float w1 = __expf(t1 >= 0.f ? t1 : 0.2f * t1);
            wsA += w0; wsB += w1;
            ac0 = fmaf(w0, bflo(u0.x), ac0); ac1 = fmaf(w0, bfhi(u0.x), ac1);
            ac2 = fmaf(w0, bflo(u0.y), ac2); ac3 = fmaf(w0, bfhi(u0.y), ac3);
            bc0 = fmaf(w1, bflo(u1.x), bc0); bc1 = fmaf(w1, bfhi(u1.x), bc1);
            bc2 = fmaf(w1, bflo(u1.y), bc2); bc3 = fmaf(w1, bfhi(u1.y), bc3);
        }
        if (i < cnt) {
            int s = __shfl(sv, i, 32);
            float t = el[(size_t)s * 4 + h] + er_h;
            float w = __expf(t >= 0.f ? t : 0.2f * t);
            uint2 u = *(const uint2*)(fbase + (size_t)s * 128);
            wsA += w;
            ac0 = fmaf(w, bflo(u.x), ac0); ac1 = fmaf(w, bfhi(u.x), ac1);
            ac2 = fmaf(w, bflo(u.y), ac2); ac3 = fmaf(w, bfhi(u.y), ac3);
        }
    }
    float wsum = wsA + wsB;
    float inv = (wsum > 0.f) ? 1.f / wsum : 0.f;   // deg-0 node -> rst = 0
    float r0 = (ac0 + bc0) * inv, r1 = (ac1 + bc1) * inv;
    float r2 = (ac2 + bc2) * inv, r3 = (ac3 + bc3) * inv;

    uint2 su = *(const uint2*)(skip_bf + (size_t)node * 128 + j);
    float s0 = bflo(su.x), s1 = bfhi(su.x), s2 = bflo(su.y), s3 = bfhi(su.y);

    float4 wg0 = *(const float4*)(Wg + j);
    float4 wg1 = *(const float4*)(Wg + 128 + j);
    float4 wg2 = *(const float4*)(Wg + 256 + j);
    float g = r0 * wg0.x + s0 * wg1.x + (r0 - s0) * wg2.x
            + r1 * wg0.y + s1 * wg1.y + (r1 - s1) * wg2.y
            + r2 * wg0.z + s2 * wg1.z + (r2 - s2) * wg2.z
            + r3 * wg0.w + s3 * wg1.w + (r3 - s3) * wg2.w;
    #pragma unroll
    for (int m = 1; m < 32; m <<= 1) g += __shfl_xor(g, m, 32);
    float gate = 1.f / (1.f + __expf(-(g + bg[0])));

    float x0 = gate * r0 + (1.f - gate) * s0;
    float x1 = gate * r1 + (1.f - gate) * s1;
    float x2 = gate * r2 + (1.f - gate) * s2;
    float x3 = gate * r3 + (1.f - gate) * s3;

    float sm = (x0 + x1) + (x2 + x3);
    float sq = (x0 * x0 + x1 * x1) + (x2 * x2 + x3 * x3);
    #pragma unroll
    for (int m = 1; m < 32; m <<= 1) {
        sm += __shfl_xor(sm, m, 32);
        sq += __shfl_xor(sq, m, 32);
    }
    float mu = sm * (1.f / 128.f);
    float var = sq * (1.f / 128.f) - mu * mu;
    float rs = rsqrtf(var + 1e-5f);
    float alpha = pa[0];
    float4 lg = *(const float4*)(lng + j);
    float4 lb = *(const float4*)(lnb + j);
    float y0 = (x0 - mu) * rs * lg.x + lb.x;
    float y1 = (x1 - mu) * rs * lg.y + lb.y;
    float y2 = (x2 - mu) * rs * lg.z + lb.z;
    float y3 = (x3 - mu) * rs * lg.w + lb.w;
    y0 = y0 >= 0.f ? y0 : alpha * y0;
    y1 = y1 >= 0.f ? y1 : alpha * y1;
    y2 = y2 >= 0.f ? y2 : alpha * y2;
    y3 = y3 >= 0.f ? y3 : alpha * y3;
    *(float4*)(out + (size_t)node * 128 + j) = make_float4(y0, y1, y2, y3);
}

extern "C" void kernel_launch(void* const* d_in, const int* in_sizes, int n_in,
                              void* d_out, int out_size, void* d_ws, size_t ws_size,
                              hipStream_t stream)
{
    const float* feat   = (const float*)d_in[0];
    const int*   src    = (const int*)d_in[1];
    const int*   dst    = (const int*)d_in[2];
    const float* Wsrc   = (const float*)d_in[3];
    const float* bsrc   = (const float*)d_in[4];
    const float* attn_l = (const float*)d_in[5];
    const float* attn_r = (const float*)d_in[6];
    const float* Wskip  = (const float*)d_in[7];
    const float* bskip  = (const float*)d_in[8];
    const float* Wg     = (const float*)d_in[9];
    const float* bg     = (const float*)d_in[10];
    const float* lng    = (const float*)d_in[11];
    const float* lnb    = (const float*)d_in[12];
    const float* pa     = (const float*)d_in[13];

    const int n = in_sizes[0] / 128;
    const int E = in_sizes[1];
    float* out = (float*)d_out;

    // workspace: el f32[4n] | er f32[4n] | feat_src bf16[128n] | skip bf16[128n]
    //  | Wb bf16[32768] | feat16 bf16[128n] | counts_p[16n] | blocksum[128]
    //  | ready[4] | row_start[n+1] | rank[E] | csr_src[E]
    float*  el       = (float*)d_ws;
    float*  er       = el + (size_t)n * 4;
    ushort* feat_src = (ushort*)(er + (size_t)n * 4);
    ushort* skip_bf  = feat_src + (size_t)n * 128;
    ushort* Wb       = skip_bf + (size_t)n * 128;
    ushort* feat16   = Wb + 32768;
    int*    counts_p  = (int*)(feat16 + (size_t)n * 128);
    int*    blocksum  = counts_p + (size_t)n * CPAD;
    int*    ready     = blocksum + 128;
    int*    row_start = ready + 4;
    int*    rank      = row_start + (n + 1);
    int*    csr_src   = rank + E;

    // zero padded counters + blocksum + ready in one memset (~6.4 MB)
    hipMemsetAsync(counts_p, 0, ((size_t)n * CPAD + 132) * sizeof(int), stream);

    int total_feat = n * 128;
    int nrb = (E + 255) / 256;            // rank blocks (first: start atomics early)
    int nfb = (total_feat + 2047) / 2048; // feat convert blocks
    k0_conv<<<nrb + nfb + 128, 256, 0, stream>>>(
        feat, Wsrc, Wskip, dst, feat16, Wb, counts_p, rank,
        nrb, nfb, total_feat, E);

    int nbs = (n + 1023) / 1024;          // scan blocks (first, co-resident)
    int nbg = (n + 31) / 32;              // GEMM blocks
    k_mega<<<nbs + nbg, 256, 0, stream>>>(
        feat16, Wb, bsrc, bskip, attn_l, attn_r, feat_src, skip_bf, el, er,
        n, E, counts_p, row_start, blocksum, ready, nbs);

    k_fill2<<<(E + 255) / 256, 256, 0, stream>>>(src, dst, rank, row_start, csr_src, E);

    k3_fused<<<(n + 7) / 8, 256, 0, stream>>>(
        row_start, csr_src, el, er, feat_src, skip_bf, Wg, bg, lng, lnb, pa, out, n);
}